// Round 2
// baseline (214.713 us; speedup 1.0000x reference)
//
#include <hip/hip_runtime.h>
#include <hip/hip_bf16.h>

// AdditiveAttention: B=8, Q=128, V=512, H=512.
// out = [context (B*Q*H) | weights (B*Q*V)] fp32.
// ws: qp [1024*512] f32 @0, vp [4096*512] f32 @2MB (10MB).
// bc dropped (softmax shift-invariant); sum_h wc[h] const also cancels.
// Score math: tanh(y)=1-2r, r=1/(2^(C*y)+1), C=2*log2(e);
//   softmax arg = -C * sum_h wc[h]*r  (consts dropped).
// R3: shared-exp2 across q-pair (e1=e0*dd); branchless RNE bf16 split.
// R4: score phase rewritten as dynamic loop over FIXED 4-step chunks with
//   statically-indexed register arrays. R1/R2's unroll+break idiom left
//   voff[16]/a0[16]/a1[16] runtime-indexed -> scratch (VGPR=40, +9.6MB
//   WRITE spill traffic). Chunking makes every index compile-time.

#define C_SCALE 2.8853900817779268f

typedef __attribute__((ext_vector_type(8))) short short8;
typedef __attribute__((ext_vector_type(4))) float f32x4;

__device__ __forceinline__ float fexp2(float x) { return __builtin_amdgcn_exp2f(x); }
__device__ __forceinline__ float frcp(float x)  { return __builtin_amdgcn_rcpf(x); }

// Branchless RNE fp32->bf16 split: hi = rne_bf16(x); lo = rne_bf16(x - hi).
__device__ __forceinline__ void bf_split(float x, short& hi, short& lo) {
  unsigned u = __builtin_bit_cast(unsigned, x);
  unsigned r = u + 0x7fffu + ((u >> 16) & 1u);
  hi = (short)(r >> 16);
  float hf = __builtin_bit_cast(float, r & 0xffff0000u);
  float lf = x - hf;
  unsigned ul = __builtin_bit_cast(unsigned, lf);
  unsigned rl = ul + 0x7fffu + ((ul >> 16) & 1u);
  lo = (short)(rl >> 16);
}

// ---------------- split-bf16 MFMA GEMM ---------------------------------------
// out[m][n] = sum_k A[m][k]*W[n][k] + bias[n].  N=K=512.
// x = hi + lo (both bf16); D = Ahi*Whi + Ahi*Wlo + Alo*Whi (lo*lo dropped).
// 64x64 tile, KC=64. by<16 -> query rows (qp), else values rows (vp).
// LDS rows padded to 72 shorts (144B).
__global__ __launch_bounds__(256, 4) void proj_gemm_mfma(
    const float* __restrict__ query, const float* __restrict__ values,
    const float* __restrict__ Wq, const float* __restrict__ Wv,
    const float* __restrict__ bq, const float* __restrict__ bv,
    float* __restrict__ qp, float* __restrict__ vp)
{
  __shared__ short sAhi[64 * 72];
  __shared__ short sAlo[64 * 72];
  __shared__ short sWhi[64 * 72];
  __shared__ short sWlo[64 * 72];

  const int t    = threadIdx.x;
  const int lane = t & 63;
  const int w    = t >> 6;                  // wave 0..3
  const int by   = blockIdx.y;
  const bool isQ = (by < 16);
  const float* A    = isQ ? query : values;
  const float* W    = isQ ? Wq : Wv;
  const float* bias = isQ ? bq : bv;
  float*       out  = isQ ? qp : vp;
  const int m0 = (isQ ? by : (by - 16)) << 6;
  const int n0 = blockIdx.x << 6;

  // staging map: thread t, iter p: row = t>>2 (64 rows), f4-col = p*4 + (t&3)
  const int srow = t >> 2, scol = t & 3;
  const float* Ap = A + (size_t)(m0 + srow) * 512 + (scol << 2);
  const float* Wp = W + (size_t)(n0 + srow) * 512 + (scol << 2);

  const int mw = (w & 1) << 5, nw = (w >> 1) << 5;   // wave's 32x32 quadrant
  const int frow = lane & 15, fquad = lane >> 4;

  f32x4 acc[2][2] = {};
  float4 pfA[4], pfW[4];
#pragma unroll
  for (int p = 0; p < 4; ++p) {
    pfA[p] = *(const float4*)(Ap + (p << 4));
    pfW[p] = *(const float4*)(Wp + (p << 4));
  }

  for (int kc = 0; kc < 512; kc += 64) {
    __syncthreads();
#pragma unroll
    for (int p = 0; p < 4; ++p) {
      float av[4] = {pfA[p].x, pfA[p].y, pfA[p].z, pfA[p].w};
      float wv[4] = {pfW[p].x, pfW[p].y, pfW[p].z, pfW[p].w};
      short4 ah, al, wh, wl;
      short* ahp = (short*)&ah; short* alp = (short*)&al;
      short* whp = (short*)&wh; short* wlp = (short*)&wl;
#pragma unroll
      for (int k = 0; k < 4; ++k) {
        bf_split(av[k], ahp[k], alp[k]);
        bf_split(wv[k], whp[k], wlp[k]);
      }
      const int ofs = srow * 72 + ((p << 2) + scol) * 4;
      *(short4*)&sAhi[ofs] = ah; *(short4*)&sAlo[ofs] = al;
      *(short4*)&sWhi[ofs] = wh; *(short4*)&sWlo[ofs] = wl;
    }
    __syncthreads();
    if (kc + 64 < 512) {
#pragma unroll
      for (int p = 0; p < 4; ++p) {
        pfA[p] = *(const float4*)(Ap + kc + 64 + (p << 4));
        pfW[p] = *(const float4*)(Wp + kc + 64 + (p << 4));
      }
    }
#pragma unroll
    for (int kb = 0; kb < 2; ++kb) {
      const int ko = kb * 32 + fquad * 8;
      short8 ahi[2], alo[2], whi[2], wlo[2];
#pragma unroll
      for (int mt = 0; mt < 2; ++mt) {
        const int r = (mw + mt * 16 + frow) * 72 + ko;
        ahi[mt] = *(const short8*)&sAhi[r];
        alo[mt] = *(const short8*)&sAlo[r];
      }
#pragma unroll
      for (int nt = 0; nt < 2; ++nt) {
        const int r = (nw + nt * 16 + frow) * 72 + ko;
        whi[nt] = *(const short8*)&sWhi[r];
        wlo[nt] = *(const short8*)&sWlo[r];
      }
#pragma unroll
      for (int mt = 0; mt < 2; ++mt)
#pragma unroll
        for (int nt = 0; nt < 2; ++nt) {
          acc[mt][nt] = __builtin_amdgcn_mfma_f32_16x16x32_bf16(
              alo[mt], whi[nt], acc[mt][nt], 0, 0, 0);
          acc[mt][nt] = __builtin_amdgcn_mfma_f32_16x16x32_bf16(
              ahi[mt], wlo[nt], acc[mt][nt], 0, 0, 0);
          acc[mt][nt] = __builtin_amdgcn_mfma_f32_16x16x32_bf16(
              ahi[mt], whi[nt], acc[mt][nt], 0, 0, 0);
        }
    }
  }

  // epilogue: C/D layout col = lane&15, row = (lane>>4)*4 + reg
#pragma unroll
  for (int nt = 0; nt < 2; ++nt) {
    const int n = n0 + nw + nt * 16 + frow;
    const float bn = bias[n];
#pragma unroll
    for (int mt = 0; mt < 2; ++mt) {
      float vreg[4] = {acc[mt][nt].x, acc[mt][nt].y, acc[mt][nt].z, acc[mt][nt].w};
#pragma unroll
      for (int r = 0; r < 4; ++r) {
        const int m = m0 + mw + mt * 16 + fquad * 4 + r;
        out[(size_t)m * 512 + n] = vreg[r] + bn;
      }
    }
  }
}

// ---------------- fused attention (no-LDS dataflow) --------------------------
// Block = (b, 2 q's), 512 threads = 8 waves; grid 512 = 2 blocks/CU.
// Score: wave w owns slots [w*4*NSTEP, ...); 4 slot-groups x 16 h-lanes.
// Slot loop = dynamic chunks of 4 steps; ALL register arrays statically
// indexed (fresh per chunk) so nothing spills. q/wc reload per chunk is L1.
// Shared-exp2: e1 = e0 * dd[h], dd = 2^(C*(q1-q0)).
// Context: wave w owns h-window [w*64, w*64+64); butterfly over g.
__global__ __launch_bounds__(512, 4) void attn_fused(
    const float* __restrict__ qp, const float* __restrict__ vp,
    const float* __restrict__ values, const int* __restrict__ mask,
    const float* __restrict__ wc,
    float* __restrict__ out_ctx, float* __restrict__ out_w)
{
  __shared__ int   idxs[512];
  __shared__ float wls[2][512];     // raw acc per (q, slot); +BIG = invalid
  __shared__ float wls2[512][2];    // final weights per slot, (q0,q1) pairs
  __shared__ int   cnt8[8];

  const int t    = threadIdx.x;
  const int lane = t & 63;
  const int w    = t >> 6;                 // 0..7
  const int b    = blockIdx.x & 7;
  const int qg   = blockIdx.x >> 3;
  const int rowbase = b * 128 + qg * 2;    // global q-row of q0

  // ---- setup: init LDS, zero out_w rows, mask compaction
  ((float*)wls)[t]        = 3.4e38f;
  ((float*)wls)[t + 512]  = 3.4e38f;
  ((float*)wls2)[t]       = 0.f;
  ((float*)wls2)[t + 512] = 0.f;
  idxs[t] = 0;
  if (t < 256) {
    float4 z = {0.f, 0.f, 0.f, 0.f};
    ((float4*)(out_w + (size_t)rowbase * 512))[t] = z;
  }
  const int mv = mask[b * 512 + t];
  const unsigned long long bal = __ballot(mv != 0);
  if (lane == 0) cnt8[w] = __popcll(bal);
  __syncthreads();
  int cnt = 0, offw = 0;
#pragma unroll
  for (int j = 0; j < 8; ++j) { if (j == w) offw = cnt; cnt += cnt8[j]; }
  if (mv) {
    int rank = __popcll(bal & ((1ull << lane) - 1ull));
    idxs[offw + rank] = t;
  }
  __syncthreads();

  // ---- score phase
  const int NSTEP = (cnt + 31) >> 5;       // 4-slot steps per wave (<=16)
  const int sbase = w * (NSTEP << 2);
  const int g  = lane >> 4;                // slot-group 0..3
  const int c4 = (lane & 15) << 2;         // h-quad base

  const float* vpb = vp + (size_t)b * 512 * 512;
  const float* qr0 = qp + (size_t)rowbase * 512;
  const float* qr1 = qr0 + 512;

  for (int i0 = 0; i0 < NSTEP; i0 += 4) {  // dynamic chunk loop
    unsigned voff[4];
    float a0[4] = {0.f, 0.f, 0.f, 0.f};
    float a1[4] = {0.f, 0.f, 0.f, 0.f};
#pragma unroll
    for (int u = 0; u < 4; ++u) {
      // tail-chunk overflow steps read a valid (garbage) slot; writes guarded.
      const int s = sbase + ((i0 + u) << 2) + g;   // < 512 always (NSTEP<=16)
      voff[u] = ((unsigned)idxs[s] << 9) + (unsigned)c4;
    }
#pragma unroll
    for (int j = 0; j < 8; ++j) {
      const int hoff = j * 64 + c4;
      const float4 q0v = *(const float4*)(qr0 + hoff);
      const float4 q1v = *(const float4*)(qr1 + hoff);
      const float4 wcv = *(const float4*)(wc + hoff);
      const unsigned jo = (unsigned)(j << 6);
      float4 vv[4];
#pragma unroll
      for (int u = 0; u < 4; ++u)
        vv[u] = *(const float4*)(vpb + (voff[u] + jo));
      const float cq0[4] = {C_SCALE * q0v.x, C_SCALE * q0v.y,
                            C_SCALE * q0v.z, C_SCALE * q0v.w};
      const float dd[4]  = {fexp2(C_SCALE * (q1v.x - q0v.x)),
                            fexp2(C_SCALE * (q1v.y - q0v.y)),
                            fexp2(C_SCALE * (q1v.z - q0v.z)),
                            fexp2(C_SCALE * (q1v.w - q0v.w))};
      const float wc4[4] = {wcv.x, wcv.y, wcv.z, wcv.w};
#pragma unroll
      for (int u = 0; u < 4; ++u) {
        const float vq[4] = {vv[u].x, vv[u].y, vv[u].z, vv[u].w};
#pragma unroll
        for (int k = 0; k < 4; ++k) {
          float x0 = __builtin_fmaf(C_SCALE, vq[k], cq0[k]);
          float e0 = fexp2(x0);
          float e1 = e0 * dd[k];
          float r0 = frcp(e0 + 1.0f);
          float r1 = frcp(e1 + 1.0f);
          a0[u] = __builtin_fmaf(wc4[k], r0, a0[u]);
          a1[u] = __builtin_fmaf(wc4[k], r1, a1[u]);
        }
      }
    }
    // per-slot reduce across the 16 lanes sharing g, then write
#pragma unroll
    for (int u = 0; u < 4; ++u) {
      const int i = i0 + u;                // <= 15 always
      float s0 = a0[u], s1 = a1[u];
#pragma unroll
      for (int off = 1; off < 16; off <<= 1) {
        s0 += __shfl_xor(s0, off, 64);
        s1 += __shfl_xor(s1, off, 64);
      }
      const int s = sbase + (i << 2) + g;
      if (i < NSTEP && (lane & 15) == i && s < cnt) {
        wls[0][s] = s0; wls[1][s] = s1;
      }
    }
  }
  __syncthreads();

  // ---- softmax: waves 0-3 -> q0, 4-7 -> q1 (dup compute; waves 0/4 write)
  {
    const int mq = (w >= 4) ? 1 : 0;
    const float* sc = wls[mq];
    float4 u0 = ((const float4*)sc)[lane * 2];
    float4 u1 = ((const float4*)sc)[lane * 2 + 1];
    float s8[8] = {u0.x, u0.y, u0.z, u0.w, u1.x, u1.y, u1.z, u1.w};
    float m = s8[0];
#pragma unroll
    for (int k = 1; k < 8; ++k) m = fminf(m, s8[k]);      // min: weight=exp2(C*(m-s))
#pragma unroll
    for (int off = 1; off < 64; off <<= 1) m = fminf(m, __shfl_xor(m, off, 64));
    float e[8], S = 0.f;
#pragma unroll
    for (int k = 0; k < 8; ++k) { e[k] = fexp2(C_SCALE * (m - s8[k])); S += e[k]; }
#pragma unroll
    for (int off = 1; off < 64; off <<= 1) S += __shfl_xor(S, off, 64);
    const float rinv = frcp(S);
    if (w == 0 || w == 4) {
      float* owq = out_w + (size_t)(rowbase + mq) * 512;
#pragma unroll
      for (int k = 0; k < 8; ++k) {
        const int s = lane * 8 + k;
        const float wgt = e[k] * rinv;                    // invalid slots -> 0
        wls2[s][mq] = wgt;
        if (s < cnt) owq[idxs[s]] = wgt;
      }
    }
  }
  __syncthreads();

  // ---- context: wave w owns h-window [w*64, w*64+64)
  const int NC = (cnt + 3) >> 2;
  const unsigned hbase = (unsigned)(w * 64 + c4);
  const float* vb = values + (size_t)b * 512 * 512;
  float c0[4] = {0.f, 0.f, 0.f, 0.f}, c1[4] = {0.f, 0.f, 0.f, 0.f};
#pragma unroll 4
  for (int i = 0; i < NC; ++i) {
    const int s = (i << 2) + g;
    const unsigned ro = ((unsigned)idxs[s] << 9) + hbase;
    const float2 wg = *(const float2*)&wls2[s][0];        // padded slots: 0
    const float4 v4 = *(const float4*)(vb + ro);
    float vv[4] = {v4.x, v4.y, v4.z, v4.w};
#pragma unroll
    for (int k = 0; k < 4; ++k) {
      c0[k] = __builtin_fmaf(wg.x, vv[k], c0[k]);
      c1[k] = __builtin_fmaf(wg.y, vv[k], c1[k]);
    }
  }
#pragma unroll
  for (int k = 0; k < 4; ++k) {                           // reduce over g
    c0[k] += __shfl_xor(c0[k], 16, 64); c0[k] += __shfl_xor(c0[k], 32, 64);
    c1[k] += __shfl_xor(c1[k], 16, 64); c1[k] += __shfl_xor(c1[k], 32, 64);
  }
  if (lane < 16) {
    float4 o0 = {c0[0], c0[1], c0[2], c0[3]};
    float4 o1 = {c1[0], c1[1], c1[2], c1[3]};
    *(float4*)(out_ctx + (size_t)rowbase * 512 + w * 64 + lane * 4)       = o0;
    *(float4*)(out_ctx + (size_t)(rowbase + 1) * 512 + w * 64 + lane * 4) = o1;
  }
}

extern "C" void kernel_launch(void* const* d_in, const int* in_sizes, int n_in,
                              void* d_out, int out_size, void* d_ws, size_t ws_size,
                              hipStream_t stream) {
  const float* query  = (const float*)d_in[0];
  const float* values = (const float*)d_in[1];
  const int*   mask   = (const int*)d_in[2];
  const float* Wq     = (const float*)d_in[3];
  const float* bq     = (const float*)d_in[4];
  const float* Wv     = (const float*)d_in[5];
  const float* bv     = (const float*)d_in[6];
  const float* wc     = (const float*)d_in[7];
  // d_in[8] = bc: no effect on outputs (softmax shift-invariance) -> dropped.

  float* out = (float*)d_out;
  float* qp  = (float*)d_ws;                 // 1024 x 512
  float* vp  = qp + (size_t)1024 * 512;      // 4096 x 512

  proj_gemm_mfma<<<dim3(8, 80), 256, 0, stream>>>(query, values, Wq, Wv, bq, bv, qp, vp);
  attn_fused<<<512, 512, 0, stream>>>(qp, vp, values, mask, wc,
                                      out, out + (size_t)8 * 128 * 512);
}

// Round 3
// 148.830 us; speedup vs baseline: 1.4427x; 1.4427x over previous
//
#include <hip/hip_runtime.h>
#include <hip/hip_bf16.h>

// AdditiveAttention: B=8, Q=128, V=512, H=512.
// out = [context (B*Q*H) | weights (B*Q*V)] fp32.
// ws: qp [1024*512] f32 @0, vp [4096*512] f32 @2MB (10MB).
// bc dropped (softmax shift-invariant); sum_h wc[h] const also cancels.
// Score math: tanh(y)=1-2r, r=1/(2^(C*y)+1), C=2*log2(e);
//   softmax arg = -C * sum_h wc[h]*r  (consts dropped).
// R3: shared-exp2 across q-pair (e1=e0*dd); branchless RNE bf16 split.
// R5: launch_bounds min-occupancy args REMOVED. Evidence: R0 (plain (512))
//   had WRITE=4.15MB = zero scratch; every (,4) variant spilled (R1: 9.6MB,
//   R2-chunked: 118MB scratch, VGPR pinned to 64 = the 8-wave/SIMD budget).
//   The hint makes regalloc squeeze to a high-occupancy VGPR target and
//   spill; grid (512 blocks = 2/CU) caps occupancy anyway. Structure
//   otherwise identical to the measured-best R1 (58.8us attn).

#define C_SCALE 2.8853900817779268f

typedef __attribute__((ext_vector_type(8))) short short8;
typedef __attribute__((ext_vector_type(4))) float f32x4;

__device__ __forceinline__ float fexp2(float x) { return __builtin_amdgcn_exp2f(x); }
__device__ __forceinline__ float frcp(float x)  { return __builtin_amdgcn_rcpf(x); }

// Branchless RNE fp32->bf16 split: hi = rne_bf16(x); lo = rne_bf16(x - hi).
__device__ __forceinline__ void bf_split(float x, short& hi, short& lo) {
  unsigned u = __builtin_bit_cast(unsigned, x);
  unsigned r = u + 0x7fffu + ((u >> 16) & 1u);
  hi = (short)(r >> 16);
  float hf = __builtin_bit_cast(float, r & 0xffff0000u);
  float lf = x - hf;
  unsigned ul = __builtin_bit_cast(unsigned, lf);
  unsigned rl = ul + 0x7fffu + ((ul >> 16) & 1u);
  lo = (short)(rl >> 16);
}

// ---------------- split-bf16 MFMA GEMM ---------------------------------------
// out[m][n] = sum_k A[m][k]*W[n][k] + bias[n].  N=K=512.
// x = hi + lo (both bf16); D = Ahi*Whi + Ahi*Wlo + Alo*Whi (lo*lo dropped).
// 64x64 tile, KC=64. by<16 -> query rows (qp), else values rows (vp).
// LDS rows padded to 72 shorts (144B).
__global__ __launch_bounds__(256) void proj_gemm_mfma(
    const float* __restrict__ query, const float* __restrict__ values,
    const float* __restrict__ Wq, const float* __restrict__ Wv,
    const float* __restrict__ bq, const float* __restrict__ bv,
    float* __restrict__ qp, float* __restrict__ vp)
{
  __shared__ short sAhi[64 * 72];
  __shared__ short sAlo[64 * 72];
  __shared__ short sWhi[64 * 72];
  __shared__ short sWlo[64 * 72];

  const int t    = threadIdx.x;
  const int lane = t & 63;
  const int w    = t >> 6;                  // wave 0..3
  const int by   = blockIdx.y;
  const bool isQ = (by < 16);
  const float* A    = isQ ? query : values;
  const float* W    = isQ ? Wq : Wv;
  const float* bias = isQ ? bq : bv;
  float*       out  = isQ ? qp : vp;
  const int m0 = (isQ ? by : (by - 16)) << 6;
  const int n0 = blockIdx.x << 6;

  // staging map: thread t, iter p: row = t>>2 (64 rows), f4-col = p*4 + (t&3)
  const int srow = t >> 2, scol = t & 3;
  const float* Ap = A + (size_t)(m0 + srow) * 512 + (scol << 2);
  const float* Wp = W + (size_t)(n0 + srow) * 512 + (scol << 2);

  const int mw = (w & 1) << 5, nw = (w >> 1) << 5;   // wave's 32x32 quadrant
  const int frow = lane & 15, fquad = lane >> 4;

  f32x4 acc[2][2] = {};
  float4 pfA[4], pfW[4];
#pragma unroll
  for (int p = 0; p < 4; ++p) {
    pfA[p] = *(const float4*)(Ap + (p << 4));
    pfW[p] = *(const float4*)(Wp + (p << 4));
  }

  for (int kc = 0; kc < 512; kc += 64) {
    __syncthreads();
#pragma unroll
    for (int p = 0; p < 4; ++p) {
      float av[4] = {pfA[p].x, pfA[p].y, pfA[p].z, pfA[p].w};
      float wv[4] = {pfW[p].x, pfW[p].y, pfW[p].z, pfW[p].w};
      short4 ah, al, wh, wl;
      short* ahp = (short*)&ah; short* alp = (short*)&al;
      short* whp = (short*)&wh; short* wlp = (short*)&wl;
#pragma unroll
      for (int k = 0; k < 4; ++k) {
        bf_split(av[k], ahp[k], alp[k]);
        bf_split(wv[k], whp[k], wlp[k]);
      }
      const int ofs = srow * 72 + ((p << 2) + scol) * 4;
      *(short4*)&sAhi[ofs] = ah; *(short4*)&sAlo[ofs] = al;
      *(short4*)&sWhi[ofs] = wh; *(short4*)&sWlo[ofs] = wl;
    }
    __syncthreads();
    if (kc + 64 < 512) {
#pragma unroll
      for (int p = 0; p < 4; ++p) {
        pfA[p] = *(const float4*)(Ap + kc + 64 + (p << 4));
        pfW[p] = *(const float4*)(Wp + kc + 64 + (p << 4));
      }
    }
#pragma unroll
    for (int kb = 0; kb < 2; ++kb) {
      const int ko = kb * 32 + fquad * 8;
      short8 ahi[2], alo[2], whi[2], wlo[2];
#pragma unroll
      for (int mt = 0; mt < 2; ++mt) {
        const int r = (mw + mt * 16 + frow) * 72 + ko;
        ahi[mt] = *(const short8*)&sAhi[r];
        alo[mt] = *(const short8*)&sAlo[r];
      }
#pragma unroll
      for (int nt = 0; nt < 2; ++nt) {
        const int r = (nw + nt * 16 + frow) * 72 + ko;
        whi[nt] = *(const short8*)&sWhi[r];
        wlo[nt] = *(const short8*)&sWlo[r];
      }
#pragma unroll
      for (int mt = 0; mt < 2; ++mt)
#pragma unroll
        for (int nt = 0; nt < 2; ++nt) {
          acc[mt][nt] = __builtin_amdgcn_mfma_f32_16x16x32_bf16(
              alo[mt], whi[nt], acc[mt][nt], 0, 0, 0);
          acc[mt][nt] = __builtin_amdgcn_mfma_f32_16x16x32_bf16(
              ahi[mt], wlo[nt], acc[mt][nt], 0, 0, 0);
          acc[mt][nt] = __builtin_amdgcn_mfma_f32_16x16x32_bf16(
              ahi[mt], whi[nt], acc[mt][nt], 0, 0, 0);
        }
    }
  }

  // epilogue: C/D layout col = lane&15, row = (lane>>4)*4 + reg
#pragma unroll
  for (int nt = 0; nt < 2; ++nt) {
    const int n = n0 + nw + nt * 16 + frow;
    const float bn = bias[n];
#pragma unroll
    for (int mt = 0; mt < 2; ++mt) {
      float vreg[4] = {acc[mt][nt].x, acc[mt][nt].y, acc[mt][nt].z, acc[mt][nt].w};
#pragma unroll
      for (int r = 0; r < 4; ++r) {
        const int m = m0 + mw + mt * 16 + fquad * 4 + r;
        out[(size_t)m * 512 + n] = vreg[r] + bn;
      }
    }
  }
}

// ---------------- fused attention (no-LDS dataflow) --------------------------
// Block = (b, 2 q's), 512 threads = 8 waves; grid 512 = 2 blocks/CU.
// Every wave computes BOTH q's (one vp read serves 2 q's).
// Score: wave w owns slots [w*4*NSTEP, ...); lane = (slot-group g = lane>>4,
//   h-quad = lane&15). vp read direct from global (L1/L2; vp[b]+values[b] =
//   2MB pinned per XCD via blockIdx&7 = b swizzle). Per-slot reduce: 4
//   butterflies over the 16 lanes sharing g. No LDS in hot loops.
// Shared-exp2: e1 = e0 * dd[h], dd = 2^(C*(q1-q0)) -- 1 exp2 per element-pair.
// Context: wave w owns h-window [w*64, w*64+64); all slots; butterfly over g.
__global__ __launch_bounds__(512) void attn_fused(
    const float* __restrict__ qp, const float* __restrict__ vp,
    const float* __restrict__ values, const int* __restrict__ mask,
    const float* __restrict__ wc,
    float* __restrict__ out_ctx, float* __restrict__ out_w)
{
  __shared__ int   idxs[512];
  __shared__ float wls[2][512];     // raw acc per (q, slot); +BIG = invalid
  __shared__ float wls2[512][2];    // final weights per slot, (q0,q1) pairs
  __shared__ int   cnt8[8];

  const int t    = threadIdx.x;
  const int lane = t & 63;
  const int w    = t >> 6;                 // 0..7
  const int b    = blockIdx.x & 7;
  const int qg   = blockIdx.x >> 3;
  const int rowbase = b * 128 + qg * 2;    // global q-row of q0

  // ---- setup: init LDS, zero out_w rows, mask compaction
  ((float*)wls)[t]        = 3.4e38f;
  ((float*)wls)[t + 512]  = 3.4e38f;
  ((float*)wls2)[t]       = 0.f;
  ((float*)wls2)[t + 512] = 0.f;
  idxs[t] = 0;
  if (t < 256) {
    float4 z = {0.f, 0.f, 0.f, 0.f};
    ((float4*)(out_w + (size_t)rowbase * 512))[t] = z;
  }
  const int mv = mask[b * 512 + t];
  const unsigned long long bal = __ballot(mv != 0);
  if (lane == 0) cnt8[w] = __popcll(bal);
  __syncthreads();
  int cnt = 0, offw = 0;
#pragma unroll
  for (int j = 0; j < 8; ++j) { if (j == w) offw = cnt; cnt += cnt8[j]; }
  if (mv) {
    int rank = __popcll(bal & ((1ull << lane) - 1ull));
    idxs[offw + rank] = t;
  }
  __syncthreads();

  // ---- score phase
  const int NSTEP = (cnt + 31) >> 5;       // 4-slot steps per wave (<=16)
  const int sbase = w * (NSTEP << 2);
  const int g  = lane >> 4;                // slot-group 0..3
  const int c4 = (lane & 15) << 2;         // h-quad base

  unsigned voff[16];                       // element offset of quad in vp[b]
  float a0[16], a1[16];
#pragma unroll
  for (int i = 0; i < 16; ++i) {
    if (i >= NSTEP) break;
    voff[i] = ((unsigned)idxs[sbase + (i << 2) + g] << 9) + (unsigned)c4;
    a0[i] = 0.f; a1[i] = 0.f;
  }

  const float* vpb = vp + (size_t)b * 512 * 512;
  const float* qr0 = qp + (size_t)rowbase * 512;
  const float* qr1 = qr0 + 512;

  for (int j = 0; j < 8; ++j) {
    const int hoff = j * 64 + c4;
    float4 q0v = *(const float4*)(qr0 + hoff);
    float4 q1v = *(const float4*)(qr1 + hoff);
    float4 wcv = *(const float4*)(wc + hoff);
    float cq0[4] = {C_SCALE * q0v.x, C_SCALE * q0v.y, C_SCALE * q0v.z, C_SCALE * q0v.w};
    // dd = 2^(C*(q1-q0)): second q's exp comes from one mul instead of exp2
    float dd[4]  = {fexp2(C_SCALE * (q1v.x - q0v.x)), fexp2(C_SCALE * (q1v.y - q0v.y)),
                    fexp2(C_SCALE * (q1v.z - q0v.z)), fexp2(C_SCALE * (q1v.w - q0v.w))};
    float wc4[4] = {wcv.x, wcv.y, wcv.z, wcv.w};
    const unsigned jo = (unsigned)(j * 64);

    float4 vcur = *(const float4*)(vpb + (voff[0] + jo));
#pragma unroll
    for (int i = 0; i < 16; ++i) {
      if (i >= NSTEP) break;
      float4 vnext = vcur;
      if (i + 1 < NSTEP)
        vnext = *(const float4*)(vpb + (voff[i + 1] + jo));
      float vv[4] = {vcur.x, vcur.y, vcur.z, vcur.w};
#pragma unroll
      for (int k = 0; k < 4; ++k) {
        float x0 = __builtin_fmaf(C_SCALE, vv[k], cq0[k]);
        float e0 = fexp2(x0);
        float e1 = e0 * dd[k];
        float r0 = frcp(e0 + 1.0f);
        float r1 = frcp(e1 + 1.0f);
        a0[i] = __builtin_fmaf(wc4[k], r0, a0[i]);
        a1[i] = __builtin_fmaf(wc4[k], r1, a1[i]);
      }
      vcur = vnext;
    }
  }

  // per-slot reduce across the 16 lanes sharing g (xor 1,2,4,8), then write
#pragma unroll
  for (int i = 0; i < 16; ++i) {
    if (i >= NSTEP) break;
    float s0 = a0[i], s1 = a1[i];
#pragma unroll
    for (int off = 1; off < 16; off <<= 1) {
      s0 += __shfl_xor(s0, off, 64);
      s1 += __shfl_xor(s1, off, 64);
    }
    const int s = sbase + (i << 2) + g;
    if ((lane & 15) == i && s < cnt) { wls[0][s] = s0; wls[1][s] = s1; }
  }
  __syncthreads();

  // ---- softmax: waves 0-3 -> q0, 4-7 -> q1 (dup compute; waves 0/4 write)
  {
    const int mq = (w >= 4) ? 1 : 0;
    const float* sc = wls[mq];
    float4 u0 = ((const float4*)sc)[lane * 2];
    float4 u1 = ((const float4*)sc)[lane * 2 + 1];
    float s8[8] = {u0.x, u0.y, u0.z, u0.w, u1.x, u1.y, u1.z, u1.w};
    float m = s8[0];
#pragma unroll
    for (int k = 1; k < 8; ++k) m = fminf(m, s8[k]);      // min: weight=exp2(C*(m-s))
#pragma unroll
    for (int off = 1; off < 64; off <<= 1) m = fminf(m, __shfl_xor(m, off, 64));
    float e[8], S = 0.f;
#pragma unroll
    for (int k = 0; k < 8; ++k) { e[k] = fexp2(C_SCALE * (m - s8[k])); S += e[k]; }
#pragma unroll
    for (int off = 1; off < 64; off <<= 1) S += __shfl_xor(S, off, 64);
    const float rinv = frcp(S);
    if (w == 0 || w == 4) {
      float* owq = out_w + (size_t)(rowbase + mq) * 512;
#pragma unroll
      for (int k = 0; k < 8; ++k) {
        const int s = lane * 8 + k;
        const float wgt = e[k] * rinv;                    // invalid slots -> 0
        wls2[s][mq] = wgt;
        if (s < cnt) owq[idxs[s]] = wgt;
      }
    }
  }
  __syncthreads();

  // ---- context: wave w owns h-window [w*64, w*64+64)
  const int NC = (cnt + 3) >> 2;
  const unsigned hbase = (unsigned)(w * 64 + c4);
  const float* vb = values + (size_t)b * 512 * 512;
  float c0[4] = {0.f, 0.f, 0.f, 0.f}, c1[4] = {0.f, 0.f, 0.f, 0.f};
#pragma unroll 4
  for (int i = 0; i < NC; ++i) {
    const int s = (i << 2) + g;
    const unsigned ro = ((unsigned)idxs[s] << 9) + hbase;
    const float2 wg = *(const float2*)&wls2[s][0];        // padded slots: 0
    const float4 v4 = *(const float4*)(vb + ro);
    float vv[4] = {v4.x, v4.y, v4.z, v4.w};
#pragma unroll
    for (int k = 0; k < 4; ++k) {
      c0[k] = __builtin_fmaf(wg.x, vv[k], c0[k]);
      c1[k] = __builtin_fmaf(wg.y, vv[k], c1[k]);
    }
  }
#pragma unroll
  for (int k = 0; k < 4; ++k) {                           // reduce over g
    c0[k] += __shfl_xor(c0[k], 16, 64); c0[k] += __shfl_xor(c0[k], 32, 64);
    c1[k] += __shfl_xor(c1[k], 16, 64); c1[k] += __shfl_xor(c1[k], 32, 64);
  }
  if (lane < 16) {
    float4 o0 = {c0[0], c0[1], c0[2], c0[3]};
    float4 o1 = {c1[0], c1[1], c1[2], c1[3]};
    *(float4*)(out_ctx + (size_t)rowbase * 512 + w * 64 + lane * 4)       = o0;
    *(float4*)(out_ctx + (size_t)(rowbase + 1) * 512 + w * 64 + lane * 4) = o1;
  }
}

extern "C" void kernel_launch(void* const* d_in, const int* in_sizes, int n_in,
                              void* d_out, int out_size, void* d_ws, size_t ws_size,
                              hipStream_t stream) {
  const float* query  = (const float*)d_in[0];
  const float* values = (const float*)d_in[1];
  const int*   mask   = (const int*)d_in[2];
  const float* Wq     = (const float*)d_in[3];
  const float* bq     = (const float*)d_in[4];
  const float* Wv     = (const float*)d_in[5];
  const float* bv     = (const float*)d_in[6];
  const float* wc     = (const float*)d_in[7];
  // d_in[8] = bc: no effect on outputs (softmax shift-invariance) -> dropped.

  float* out = (float*)d_out;
  float* qp  = (float*)d_ws;                 // 1024 x 512
  float* vp  = qp + (size_t)1024 * 512;      // 4096 x 512

  proj_gemm_mfma<<<dim3(8, 80), 256, 0, stream>>>(query, values, Wq, Wv, bq, bv, qp, vp);
  attn_fused<<<512, 512, 0, stream>>>(qp, vp, values, mask, wc,
                                      out, out + (size_t)8 * 128 * 512);
}

// Round 4
// 145.792 us; speedup vs baseline: 1.4727x; 1.0208x over previous
//
#include <hip/hip_runtime.h>
#include <hip/hip_bf16.h>

// AdditiveAttention: B=8, Q=128, V=512, H=512.
// out = [context (B*Q*H) | weights (B*Q*V)] fp32.
// ws: qp [1024*512] f32 @0, vp [4096*512] f32 @2MB (10MB).
// bc dropped (softmax shift-invariant); sum_h wc[h] const also cancels.
// Score math: tanh(y)=1-2r, r=1/(2^(C*y)+1), C=2*log2(e);
//   softmax arg = -C * sum_h wc[h]*r  (consts dropped).
// R5: plain launch_bounds everywhere. (,4) hints caused scratch spills
//   (R1: 9.6MB, R2: 118MB); R3 (plain) = zero scratch, attn 58.4us.
// R6: score phase = chunks of 4 slots (j-loop inside, statically-indexed
//   arrays, fresh per chunk) + 1-slot tail loop (no wasted compute).
//   R3's VGPR=44 < 48 live array regs => arrays lived in AGPRs with
//   accvgpr shuffles on every accumulate; chunking fits them in VGPRs.
//   R2's chunk regression was the (,4) squeeze, not chunking (R3 proved).
// + pair-rcp: P=rcp((e0+1)(e1+1)), r0=(e1+1)P, r1=(e0+1)P (3->2 trans/elem).
// + proj bf_split: lo truncated (err 2^-17|x|, tolerance-safe), hi stays RNE.

#define C_SCALE 2.8853900817779268f

typedef __attribute__((ext_vector_type(8))) short short8;
typedef __attribute__((ext_vector_type(4))) float f32x4;

__device__ __forceinline__ float fexp2(float x) { return __builtin_amdgcn_exp2f(x); }
__device__ __forceinline__ float frcp(float x)  { return __builtin_amdgcn_rcpf(x); }

// fp32->bf16 split: hi = RNE(x); lo = trunc_bf16(x - hi).
__device__ __forceinline__ void bf_split(float x, short& hi, short& lo) {
  unsigned u = __builtin_bit_cast(unsigned, x);
  unsigned r = u + 0x7fffu + ((u >> 16) & 1u);
  hi = (short)(r >> 16);
  float hf = __builtin_bit_cast(float, r & 0xffff0000u);
  lo = (short)(__builtin_bit_cast(unsigned, x - hf) >> 16);
}

// ---------------- split-bf16 MFMA GEMM ---------------------------------------
// out[m][n] = sum_k A[m][k]*W[n][k] + bias[n].  N=K=512.
// x = hi + lo (both bf16); D = Ahi*Whi + Ahi*Wlo + Alo*Whi (lo*lo dropped).
// 64x64 tile, KC=64. by<16 -> query rows (qp), else values rows (vp).
// LDS rows padded to 72 shorts (144B).
__global__ __launch_bounds__(256) void proj_gemm_mfma(
    const float* __restrict__ query, const float* __restrict__ values,
    const float* __restrict__ Wq, const float* __restrict__ Wv,
    const float* __restrict__ bq, const float* __restrict__ bv,
    float* __restrict__ qp, float* __restrict__ vp)
{
  __shared__ short sAhi[64 * 72];
  __shared__ short sAlo[64 * 72];
  __shared__ short sWhi[64 * 72];
  __shared__ short sWlo[64 * 72];

  const int t    = threadIdx.x;
  const int lane = t & 63;
  const int w    = t >> 6;                  // wave 0..3
  const int by   = blockIdx.y;
  const bool isQ = (by < 16);
  const float* A    = isQ ? query : values;
  const float* W    = isQ ? Wq : Wv;
  const float* bias = isQ ? bq : bv;
  float*       out  = isQ ? qp : vp;
  const int m0 = (isQ ? by : (by - 16)) << 6;
  const int n0 = blockIdx.x << 6;

  // staging map: thread t, iter p: row = t>>2 (64 rows), f4-col = p*4 + (t&3)
  const int srow = t >> 2, scol = t & 3;
  const float* Ap = A + (size_t)(m0 + srow) * 512 + (scol << 2);
  const float* Wp = W + (size_t)(n0 + srow) * 512 + (scol << 2);

  const int mw = (w & 1) << 5, nw = (w >> 1) << 5;   // wave's 32x32 quadrant
  const int frow = lane & 15, fquad = lane >> 4;

  f32x4 acc[2][2] = {};
  float4 pfA[4], pfW[4];
#pragma unroll
  for (int p = 0; p < 4; ++p) {
    pfA[p] = *(const float4*)(Ap + (p << 4));
    pfW[p] = *(const float4*)(Wp + (p << 4));
  }

  for (int kc = 0; kc < 512; kc += 64) {
    __syncthreads();
#pragma unroll
    for (int p = 0; p < 4; ++p) {
      float av[4] = {pfA[p].x, pfA[p].y, pfA[p].z, pfA[p].w};
      float wv[4] = {pfW[p].x, pfW[p].y, pfW[p].z, pfW[p].w};
      short4 ah, al, wh, wl;
      short* ahp = (short*)&ah; short* alp = (short*)&al;
      short* whp = (short*)&wh; short* wlp = (short*)&wl;
#pragma unroll
      for (int k = 0; k < 4; ++k) {
        bf_split(av[k], ahp[k], alp[k]);
        bf_split(wv[k], whp[k], wlp[k]);
      }
      const int ofs = srow * 72 + ((p << 2) + scol) * 4;
      *(short4*)&sAhi[ofs] = ah; *(short4*)&sAlo[ofs] = al;
      *(short4*)&sWhi[ofs] = wh; *(short4*)&sWlo[ofs] = wl;
    }
    __syncthreads();
    if (kc + 64 < 512) {
#pragma unroll
      for (int p = 0; p < 4; ++p) {
        pfA[p] = *(const float4*)(Ap + kc + 64 + (p << 4));
        pfW[p] = *(const float4*)(Wp + kc + 64 + (p << 4));
      }
    }
#pragma unroll
    for (int kb = 0; kb < 2; ++kb) {
      const int ko = kb * 32 + fquad * 8;
      short8 ahi[2], alo[2], whi[2], wlo[2];
#pragma unroll
      for (int mt = 0; mt < 2; ++mt) {
        const int r = (mw + mt * 16 + frow) * 72 + ko;
        ahi[mt] = *(const short8*)&sAhi[r];
        alo[mt] = *(const short8*)&sAlo[r];
      }
#pragma unroll
      for (int nt = 0; nt < 2; ++nt) {
        const int r = (nw + nt * 16 + frow) * 72 + ko;
        whi[nt] = *(const short8*)&sWhi[r];
        wlo[nt] = *(const short8*)&sWlo[r];
      }
#pragma unroll
      for (int mt = 0; mt < 2; ++mt)
#pragma unroll
        for (int nt = 0; nt < 2; ++nt) {
          acc[mt][nt] = __builtin_amdgcn_mfma_f32_16x16x32_bf16(
              alo[mt], whi[nt], acc[mt][nt], 0, 0, 0);
          acc[mt][nt] = __builtin_amdgcn_mfma_f32_16x16x32_bf16(
              ahi[mt], wlo[nt], acc[mt][nt], 0, 0, 0);
          acc[mt][nt] = __builtin_amdgcn_mfma_f32_16x16x32_bf16(
              ahi[mt], whi[nt], acc[mt][nt], 0, 0, 0);
        }
    }
  }

  // epilogue: C/D layout col = lane&15, row = (lane>>4)*4 + reg
#pragma unroll
  for (int nt = 0; nt < 2; ++nt) {
    const int n = n0 + nw + nt * 16 + frow;
    const float bn = bias[n];
#pragma unroll
    for (int mt = 0; mt < 2; ++mt) {
      float vreg[4] = {acc[mt][nt].x, acc[mt][nt].y, acc[mt][nt].z, acc[mt][nt].w};
#pragma unroll
      for (int r = 0; r < 4; ++r) {
        const int m = m0 + mw + mt * 16 + fquad * 4 + r;
        out[(size_t)m * 512 + n] = vreg[r] + bn;
      }
    }
  }
}

// ---------------- fused attention score chunk --------------------------------
// Processes NU consecutive slot-steps for one wave: full (j=0..7) h-sweep,
// statically-indexed register arrays, then 16-lane butterfly reduce + write.
template<int NU>
__device__ __forceinline__ void score_chunk(
    const float* __restrict__ vpb, const float* __restrict__ qr0,
    const float* __restrict__ qr1, const float* __restrict__ wc,
    const int* idxs, float* wls0, float* wls1,
    int sbase, int i0, int g, int c4, int cnt, int lane)
{
  unsigned voff[NU];
  float a0[NU], a1[NU];
#pragma unroll
  for (int u = 0; u < NU; ++u) {
    const int s = (sbase + ((i0 + u) << 2) + g) & 511;
    voff[u] = ((unsigned)idxs[s] << 9) + (unsigned)c4;
    a0[u] = 0.f; a1[u] = 0.f;
  }
#pragma unroll
  for (int j = 0; j < 8; ++j) {
    const int hoff = (j << 6) + c4;
    const float4 q0v = *(const float4*)(qr0 + hoff);
    const float4 q1v = *(const float4*)(qr1 + hoff);
    const float4 wcv = *(const float4*)(wc + hoff);
    const unsigned jo = (unsigned)(j << 6);
    float4 vv[NU];
#pragma unroll
    for (int u = 0; u < NU; ++u)
      vv[u] = *(const float4*)(vpb + (voff[u] + jo));
    const float cq0[4] = {C_SCALE * q0v.x, C_SCALE * q0v.y,
                          C_SCALE * q0v.z, C_SCALE * q0v.w};
    const float dd[4]  = {fexp2(C_SCALE * (q1v.x - q0v.x)),
                          fexp2(C_SCALE * (q1v.y - q0v.y)),
                          fexp2(C_SCALE * (q1v.z - q0v.z)),
                          fexp2(C_SCALE * (q1v.w - q0v.w))};
    const float wc4[4] = {wcv.x, wcv.y, wcv.z, wcv.w};
#pragma unroll
    for (int u = 0; u < NU; ++u) {
      const float vq[4] = {vv[u].x, vv[u].y, vv[u].z, vv[u].w};
#pragma unroll
      for (int k = 0; k < 4; ++k) {
        float x0 = __builtin_fmaf(C_SCALE, vq[k], cq0[k]);
        float e0 = fexp2(x0);
        float e1 = e0 * dd[k];
        float d0 = e0 + 1.0f;
        float d1 = e1 + 1.0f;
        float P  = frcp(d0 * d1);          // pair-rcp: 1 trans for both q's
        a0[u] = __builtin_fmaf(wc4[k] * d1, P, a0[u]);
        a1[u] = __builtin_fmaf(wc4[k] * d0, P, a1[u]);
      }
    }
  }
#pragma unroll
  for (int u = 0; u < NU; ++u) {
    const int i = i0 + u;                  // <= 15 (NSTEP <= 16)
    float s0 = a0[u], s1 = a1[u];
#pragma unroll
    for (int off = 1; off < 16; off <<= 1) {
      s0 += __shfl_xor(s0, off, 64);
      s1 += __shfl_xor(s1, off, 64);
    }
    const int s = sbase + (i << 2) + g;
    if ((lane & 15) == i && s < cnt) { wls0[s] = s0; wls1[s] = s1; }
  }
}

// ---------------- fused attention (no-LDS dataflow) --------------------------
// Block = (b, 2 q's), 512 threads = 8 waves; grid 512 = 2 blocks/CU.
// Score: wave w owns slots [w*4*NSTEP, ...); 4 slot-groups x 16 h-lanes;
//   chunk-of-4 loop + 1-slot tail (exact coverage, no wasted compute).
// Context: wave w owns h-window [w*64, w*64+64); butterfly over g.
__global__ __launch_bounds__(512) void attn_fused(
    const float* __restrict__ qp, const float* __restrict__ vp,
    const float* __restrict__ values, const int* __restrict__ mask,
    const float* __restrict__ wc,
    float* __restrict__ out_ctx, float* __restrict__ out_w)
{
  __shared__ int   idxs[512];
  __shared__ float wls[2][512];     // raw acc per (q, slot); +BIG = invalid
  __shared__ float wls2[512][2];    // final weights per slot, (q0,q1) pairs
  __shared__ int   cnt8[8];

  const int t    = threadIdx.x;
  const int lane = t & 63;
  const int w    = t >> 6;                 // 0..7
  const int b    = blockIdx.x & 7;
  const int qg   = blockIdx.x >> 3;
  const int rowbase = b * 128 + qg * 2;    // global q-row of q0

  // ---- setup: init LDS, zero out_w rows, mask compaction
  ((float*)wls)[t]        = 3.4e38f;
  ((float*)wls)[t + 512]  = 3.4e38f;
  ((float*)wls2)[t]       = 0.f;
  ((float*)wls2)[t + 512] = 0.f;
  idxs[t] = 0;
  if (t < 256) {
    float4 z = {0.f, 0.f, 0.f, 0.f};
    ((float4*)(out_w + (size_t)rowbase * 512))[t] = z;
  }
  const int mv = mask[b * 512 + t];
  const unsigned long long bal = __ballot(mv != 0);
  if (lane == 0) cnt8[w] = __popcll(bal);
  __syncthreads();
  int cnt = 0, offw = 0;
#pragma unroll
  for (int j = 0; j < 8; ++j) { if (j == w) offw = cnt; cnt += cnt8[j]; }
  if (mv) {
    int rank = __popcll(bal & ((1ull << lane) - 1ull));
    idxs[offw + rank] = t;
  }
  __syncthreads();

  // ---- score phase
  const int NSTEP = (cnt + 31) >> 5;       // 4-slot steps per wave (<=16)
  const int sbase = w * (NSTEP << 2);
  const int g  = lane >> 4;                // slot-group 0..3
  const int c4 = (lane & 15) << 2;         // h-quad base

  const float* vpb = vp + (size_t)b * 512 * 512;
  const float* qr0 = qp + (size_t)rowbase * 512;
  const float* qr1 = qr0 + 512;

  int i0 = 0;
  for (; i0 + 4 <= NSTEP; i0 += 4)
    score_chunk<4>(vpb, qr0, qr1, wc, idxs, wls[0], wls[1],
                   sbase, i0, g, c4, cnt, lane);
  for (; i0 < NSTEP; ++i0)
    score_chunk<1>(vpb, qr0, qr1, wc, idxs, wls[0], wls[1],
                   sbase, i0, g, c4, cnt, lane);
  __syncthreads();

  // ---- softmax: waves 0-3 -> q0, 4-7 -> q1 (dup compute; waves 0/4 write)
  {
    const int mq = (w >= 4) ? 1 : 0;
    const float* sc = wls[mq];
    float4 u0 = ((const float4*)sc)[lane * 2];
    float4 u1 = ((const float4*)sc)[lane * 2 + 1];
    float s8[8] = {u0.x, u0.y, u0.z, u0.w, u1.x, u1.y, u1.z, u1.w};
    float m = s8[0];
#pragma unroll
    for (int k = 1; k < 8; ++k) m = fminf(m, s8[k]);      // min: weight=exp2(C*(m-s))
#pragma unroll
    for (int off = 1; off < 64; off <<= 1) m = fminf(m, __shfl_xor(m, off, 64));
    float e[8], S = 0.f;
#pragma unroll
    for (int k = 0; k < 8; ++k) { e[k] = fexp2(C_SCALE * (m - s8[k])); S += e[k]; }
#pragma unroll
    for (int off = 1; off < 64; off <<= 1) S += __shfl_xor(S, off, 64);
    const float rinv = frcp(S);
    if (w == 0 || w == 4) {
      float* owq = out_w + (size_t)(rowbase + mq) * 512;
#pragma unroll
      for (int k = 0; k < 8; ++k) {
        const int s = lane * 8 + k;
        const float wgt = e[k] * rinv;                    // invalid slots -> 0
        wls2[s][mq] = wgt;
        if (s < cnt) owq[idxs[s]] = wgt;
      }
    }
  }
  __syncthreads();

  // ---- context: wave w owns h-window [w*64, w*64+64)
  const int NC = (cnt + 3) >> 2;
  const unsigned hbase = (unsigned)(w * 64 + c4);
  const float* vb = values + (size_t)b * 512 * 512;
  float c0[4] = {0.f, 0.f, 0.f, 0.f}, c1[4] = {0.f, 0.f, 0.f, 0.f};
#pragma unroll 4
  for (int i = 0; i < NC; ++i) {
    const int s = (i << 2) + g;
    const unsigned ro = ((unsigned)idxs[s] << 9) + hbase;
    const float2 wg = *(const float2*)&wls2[s][0];        // padded slots: 0
    const float4 v4 = *(const float4*)(vb + ro);
    float vv[4] = {v4.x, v4.y, v4.z, v4.w};
#pragma unroll
    for (int k = 0; k < 4; ++k) {
      c0[k] = __builtin_fmaf(wg.x, vv[k], c0[k]);
      c1[k] = __builtin_fmaf(wg.y, vv[k], c1[k]);
    }
  }
#pragma unroll
  for (int k = 0; k < 4; ++k) {                           // reduce over g
    c0[k] += __shfl_xor(c0[k], 16, 64); c0[k] += __shfl_xor(c0[k], 32, 64);
    c1[k] += __shfl_xor(c1[k], 16, 64); c1[k] += __shfl_xor(c1[k], 32, 64);
  }
  if (lane < 16) {
    float4 o0 = {c0[0], c0[1], c0[2], c0[3]};
    float4 o1 = {c1[0], c1[1], c1[2], c1[3]};
    *(float4*)(out_ctx + (size_t)rowbase * 512 + w * 64 + lane * 4)       = o0;
    *(float4*)(out_ctx + (size_t)(rowbase + 1) * 512 + w * 64 + lane * 4) = o1;
  }
}

extern "C" void kernel_launch(void* const* d_in, const int* in_sizes, int n_in,
                              void* d_out, int out_size, void* d_ws, size_t ws_size,
                              hipStream_t stream) {
  const float* query  = (const float*)d_in[0];
  const float* values = (const float*)d_in[1];
  const int*   mask   = (const int*)d_in[2];
  const float* Wq     = (const float*)d_in[3];
  const float* bq     = (const float*)d_in[4];
  const float* Wv     = (const float*)d_in[5];
  const float* bv     = (const float*)d_in[6];
  const float* wc     = (const float*)d_in[7];
  // d_in[8] = bc: no effect on outputs (softmax shift-invariance) -> dropped.

  float* out = (float*)d_out;
  float* qp  = (float*)d_ws;                 // 1024 x 512
  float* vp  = qp + (size_t)1024 * 512;      // 4096 x 512

  proj_gemm_mfma<<<dim3(8, 80), 256, 0, stream>>>(query, values, Wq, Wv, bq, bv, qp, vp);
  attn_fused<<<512, 512, 0, stream>>>(qp, vp, values, mask, wc,
                                      out, out + (size_t)8 * 128 * 512);
}